// Round 7
// baseline (219.464 us; speedup 1.0000x reference)
//
#include <hip/hip_runtime.h>
#include <hip/hip_bf16.h>

typedef __attribute__((ext_vector_type(4))) float f32x4;
typedef __attribute__((ext_vector_type(8))) short bf16x8;
typedef __attribute__((ext_vector_type(4))) short bf16x4;
typedef __attribute__((ext_vector_type(2))) unsigned int u32x2;

#define D 128
#define BM 64

__device__ __forceinline__ unsigned short f2bf(float f){
  union { float f; unsigned int i; } c; c.f = f;
  unsigned int i = c.i;
  i += 0x7fffu + ((i >> 16) & 1u);   // round-to-nearest-even
  return (unsigned short)(i >> 16);
}
__device__ __forceinline__ float bf2f(unsigned short u){
  union { float f; unsigned int i; } c; c.i = ((unsigned int)u) << 16; return c.f;
}
// pack two floats -> 2x bf16 in one u32 (v_cvt_pk_bf16_f32)
__device__ __forceinline__ unsigned int pk2(float a, float b){
  __hip_bfloat162 t = __float22bfloat162_rn(make_float2(a, b));
  return *reinterpret_cast<unsigned int*>(&t);
}
__device__ __forceinline__ float rcp_f(float x){ return __builtin_amdgcn_rcpf(x); }
__device__ __forceinline__ float exp2_f(float x){ return __builtin_amdgcn_exp2f(x); }
// sigmoid via v_exp+v_rcp: inf-safe
__device__ __forceinline__ float sigmoid_f(float t){
  return rcp_f(1.0f + exp2_f(-1.442695041f * t));
}
// tanh = 2*sigmoid(2t)-1: inf-safe
__device__ __forceinline__ float tanh_f(float t){
  return __builtin_fmaf(2.0f, rcp_f(1.0f + exp2_f(-2.885390082f * t)), -1.0f);
}

// Pack W[k=256][n=128] fp32 -> bf16 MFMA fragments:
// frag f = nf*8+kk ; lane l holds col = nf*16+(l&15), k = kk*32+(l>>4)*8+j (j=0..7)
// Used as the A-operand (A = W^T slice): lane l = outcol l&15, 8 consecutive k.
__global__ void prep_weights(const float* __restrict__ Wr, const float* __restrict__ Wz,
                             const float* __restrict__ Wh, unsigned short* __restrict__ wp)
{
  int w = blockIdx.x >> 6;          // 0:Wr 1:Wz 2:Wh
  int f = blockIdx.x & 63;          // nf*8 + kk
  int l = threadIdx.x;              // 0..63
  const float* src = (w == 0) ? Wr : ((w == 1) ? Wz : Wh);
  int nf = f >> 3, kk = f & 7;
  int col = nf * 16 + (l & 15);
  int k0  = kk * 32 + (l >> 4) * 8;
  unsigned short* dst = wp + w * 32768 + (f * 64 + l) * 8;
#pragma unroll
  for (int j = 0; j < 8; ++j)
    dst[j] = f2bf(src[(k0 + j) * D + col]);
}

// 32KB LDS/block; 4 blocks/CU is the HW max here (R6: 5 doesn't fit, spills instead).
__global__ __launch_bounds__(256, 4) void gru_fused(
    const float* __restrict__ x, const float* __restrict__ h,
    const float* __restrict__ brp, const float* __restrict__ bzp, const float* __restrict__ bhp,
    const unsigned short* __restrict__ wp, float* __restrict__ out)
{
  // A1: xh bf16 [64 rows][256 k] XOR-swizzled (32KB). r*h_tan overwrites the h-half in place.
  // P: f32 row-sumsq partials [64][4] (1KB), overlays A1 after all stage-2 reads.
  __shared__ __align__(16) unsigned char A1[BM * 512];
  float* P = (float*)A1;

  const int tid = threadIdx.x;
  const int w   = tid >> 6;
  const int l   = tid & 63;
  const int l15 = l & 15;
  const int lq  = l >> 4;
  const size_t row0 = (size_t)blockIdx.x * BM;

  const unsigned short* pwr = wp + w * 8192;
  const unsigned short* pwz = wp + 32768 + w * 8192;
  const unsigned short* pwh = wp + 65536 + w * 8192;

  // ---------- phase 1: logmap0(x), logmap0(h) -> A1 bf16 (swizzled) ----------
  // Interleaved (x then h) to keep live VGPRs low — batching both spilled (R4).
  {
    const int row = tid >> 2;
    const int q   = tid & 3;
    const f32x4* xr = (const f32x4*)(x + (row0 + row) * D);
    const f32x4* hr = (const f32x4*)(h + (row0 + row) * D);
    f32x4 v[8];
    float ss = 0.f;
#pragma unroll
    for (int j = 0; j < 8; ++j){
      v[j] = xr[j * 4 + q];
      ss += v[j][0]*v[j][0] + v[j][1]*v[j][1] + v[j][2]*v[j][2] + v[j][3]*v[j][3];
    }
    ss += __shfl_xor(ss, 1, 64);
    ss += __shfl_xor(ss, 2, 64);
    // atanh(n)/n = 0.5*ln2*log2((1+n)*rcp(1-n)) * rcp(n)
    float n = __builtin_amdgcn_sqrtf(ss);
    float s = 1.f;
    if (n > 1e-20f)
      s = 0.34657359f * __builtin_amdgcn_logf((1.f + n) * rcp_f(1.f - n)) * rcp_f(n);
#pragma unroll
    for (int j = 0; j < 8; ++j){
      unsigned int byte = (unsigned)(row * 512 + (4 * j + q) * 8) ^ (unsigned)((row & 7) << 4);
      u32x2 pk; pk[0] = pk2(v[j][0] * s, v[j][1] * s); pk[1] = pk2(v[j][2] * s, v[j][3] * s);
      *(u32x2*)(A1 + byte) = pk;
    }
    ss = 0.f;
#pragma unroll
    for (int j = 0; j < 8; ++j){
      v[j] = hr[j * 4 + q];
      ss += v[j][0]*v[j][0] + v[j][1]*v[j][1] + v[j][2]*v[j][2] + v[j][3]*v[j][3];
    }
    ss += __shfl_xor(ss, 1, 64);
    ss += __shfl_xor(ss, 2, 64);
    n = __builtin_amdgcn_sqrtf(ss);
    s = 1.f;
    if (n > 1e-20f)
      s = 0.34657359f * __builtin_amdgcn_logf((1.f + n) * rcp_f(1.f - n)) * rcp_f(n);
#pragma unroll
    for (int j = 0; j < 8; ++j){
      unsigned int byte = (unsigned)(row * 512 + 256 + (4 * j + q) * 8) ^ (unsigned)((row & 7) << 4);
      u32x2 pk; pk[0] = pk2(v[j][0] * s, v[j][1] * s); pk[1] = pk2(v[j][2] * s, v[j][3] * s);
      *(u32x2*)(A1 + byte) = pk;
    }
  }

  // prefetch kk=0 stage-1 weight frags: VMEM latency overlaps barrier drain
  bf16x8 nwr0 = *(const bf16x8*)(pwr + 0 * 512 + l * 8);
  bf16x8 nwr1 = *(const bf16x8*)(pwr + 4096 + 0 * 512 + l * 8);
  bf16x8 nwz0 = *(const bf16x8*)(pwz + 0 * 512 + l * 8);
  bf16x8 nwz1 = *(const bf16x8*)(pwz + 4096 + 0 * 512 + l * 8);

  __syncthreads();   // (1) A1 populated

  // ---------- stage 1a: r,z = xh @ {Wr,Wz}, full K, software-pipelined weights ----------
  // wave w -> outcols [w*32, w*32+32), lane: row=m*16+l15, cols c0+{0..3}.
  f32x4 ar0[4], ar1[4], az0[4], az1[4];
#pragma unroll
  for (int m = 0; m < 4; ++m){ ar0[m] = 0; ar1[m] = 0; az0[m] = 0; az1[m] = 0; }

#pragma unroll
  for (int kk = 0; kk < 8; ++kk){
    const bf16x8 wr0 = nwr0, wr1 = nwr1, wz0 = nwz0, wz1 = nwz1;
    if (kk < 7){
      nwr0 = *(const bf16x8*)(pwr + (kk + 1) * 512 + l * 8);
      nwr1 = *(const bf16x8*)(pwr + 4096 + (kk + 1) * 512 + l * 8);
      nwz0 = *(const bf16x8*)(pwz + (kk + 1) * 512 + l * 8);
      nwz1 = *(const bf16x8*)(pwz + 4096 + (kk + 1) * 512 + l * 8);
    }
#pragma unroll
    for (int m = 0; m < 4; ++m){
      const int row = m * 16 + l15;
      unsigned int byte = (unsigned)(row * 512 + (kk * 32 + lq * 8) * 2) ^ (unsigned)((row & 7) << 4);
      const bf16x8 b = *(const bf16x8*)(A1 + byte);
      ar0[m] = __builtin_amdgcn_mfma_f32_16x16x32_bf16(wr0, b, ar0[m], 0, 0, 0);
      ar1[m] = __builtin_amdgcn_mfma_f32_16x16x32_bf16(wr1, b, ar1[m], 0, 0, 0);
      az0[m] = __builtin_amdgcn_mfma_f32_16x16x32_bf16(wz0, b, az0[m], 0, 0, 0);
      az1[m] = __builtin_amdgcn_mfma_f32_16x16x32_bf16(wz1, b, az1[m], 0, 0, 0);
    }
  }

  // ---------- epilogue 1: r,z; rh packed; ht stashed (ar/az die here) ----------
  const int c00 = w * 32 + lq * 4;
  const int c01 = c00 + 16;
  const f32x4 brv0 = *(const f32x4*)(brp + c00);
  const f32x4 brv1 = *(const f32x4*)(brp + c01);
  const f32x4 bzv0 = *(const f32x4*)(bzp + c00);
  const f32x4 bzv1 = *(const f32x4*)(bzp + c01);

  f32x4 zk0[4], zk1[4];
  u32x2 htp0[4], htp1[4];   // packed bf16 h_tan, 4 consecutive cols
  u32x2 rhp0[4], rhp1[4];   // packed bf16 r*h_tan
#pragma unroll
  for (int m = 0; m < 4; ++m){
    const int row = m * 16 + l15;
    const unsigned int swz = (unsigned)((row & 7) << 4);
    const bf16x4 h40 = *(const bf16x4*)(A1 + ((unsigned)(row * 512 + (128 + c00) * 2) ^ swz));
    const bf16x4 h41 = *(const bf16x4*)(A1 + ((unsigned)(row * 512 + (128 + c01) * 2) ^ swz));
    htp0[m] = *(const u32x2*)&h40;
    htp1[m] = *(const u32x2*)&h41;
    float rh0[4], rh1[4];
#pragma unroll
    for (int reg = 0; reg < 4; ++reg){
      float r0 = sigmoid_f(ar0[m][reg] + brv0[reg]);
      float r1 = sigmoid_f(ar1[m][reg] + brv1[reg]);
      zk0[m][reg] = sigmoid_f(az0[m][reg] + bzv0[reg]);
      zk1[m][reg] = sigmoid_f(az1[m][reg] + bzv1[reg]);
      rh0[reg] = r0 * bf2f((unsigned short)h40[reg]);
      rh1[reg] = r1 * bf2f((unsigned short)h41[reg]);
    }
    rhp0[m][0] = pk2(rh0[0], rh0[1]); rhp0[m][1] = pk2(rh0[2], rh0[3]);
    rhp1[m][0] = pk2(rh1[0], rh1[1]); rhp1[m][1] = pk2(rh1[2], rh1[3]);
  }

  // ---------- stage 1b: x_tan @ Wh[0:128] (independent of r) — pre-barrier overlap ----------
  f32x4 ah0[4], ah1[4];
#pragma unroll
  for (int m = 0; m < 4; ++m){ ah0[m] = 0; ah1[m] = 0; }
  bf16x8 nwh0 = *(const bf16x8*)(pwh + 0 * 512 + l * 8);
  bf16x8 nwh1 = *(const bf16x8*)(pwh + 4096 + 0 * 512 + l * 8);
#pragma unroll
  for (int kk = 0; kk < 4; ++kk){
    const bf16x8 wh0 = nwh0, wh1 = nwh1;
    {
      const int kn = (kk < 3) ? (kk + 1) : 4;   // last prefetch targets stage-2's kk=4
      nwh0 = *(const bf16x8*)(pwh + kn * 512 + l * 8);
      nwh1 = *(const bf16x8*)(pwh + 4096 + kn * 512 + l * 8);
    }
#pragma unroll
    for (int m = 0; m < 4; ++m){
      const int row = m * 16 + l15;
      unsigned int byte = (unsigned)(row * 512 + (kk * 32 + lq * 8) * 2) ^ (unsigned)((row & 7) << 4);
      const bf16x8 b = *(const bf16x8*)(A1 + byte);
      ah0[m] = __builtin_amdgcn_mfma_f32_16x16x32_bf16(wh0, b, ah0[m], 0, 0, 0);
      ah1[m] = __builtin_amdgcn_mfma_f32_16x16x32_bf16(wh1, b, ah1[m], 0, 0, 0);
    }
  }

  __syncthreads();   // (2) all stage-1 LDS reads complete before in-place overwrite

#pragma unroll
  for (int m = 0; m < 4; ++m){
    const int row = m * 16 + l15;
    const unsigned int swz = (unsigned)((row & 7) << 4);
    *(u32x2*)(A1 + ((unsigned)(row * 512 + (128 + c00) * 2) ^ swz)) = rhp0[m];
    *(u32x2*)(A1 + ((unsigned)(row * 512 + (128 + c01) * 2) ^ swz)) = rhp1[m];
  }
  __syncthreads();   // (3) A1 h-half now holds r*h_tan

  // ---------- stage 2: += (r*h_tan) @ Wh[128:256] — halved post-barrier tail ----------
#pragma unroll
  for (int kk = 4; kk < 8; ++kk){
    const bf16x8 wh0 = nwh0, wh1 = nwh1;
    if (kk < 7){
      nwh0 = *(const bf16x8*)(pwh + (kk + 1) * 512 + l * 8);
      nwh1 = *(const bf16x8*)(pwh + 4096 + (kk + 1) * 512 + l * 8);
    }
#pragma unroll
    for (int m = 0; m < 4; ++m){
      const int row = m * 16 + l15;
      unsigned int byte = (unsigned)(row * 512 + (kk * 32 + lq * 8) * 2) ^ (unsigned)((row & 7) << 4);
      const bf16x8 b = *(const bf16x8*)(A1 + byte);
      ah0[m] = __builtin_amdgcn_mfma_f32_16x16x32_bf16(wh0, b, ah0[m], 0, 0, 0);
      ah1[m] = __builtin_amdgcn_mfma_f32_16x16x32_bf16(wh1, b, ah1[m], 0, 0, 0);
    }
  }

  // ---------- epilogue 2: h_new_tan in regs ----------
  const f32x4 bhv0 = *(const f32x4*)(bhp + c00);
  const f32x4 bhv1 = *(const f32x4*)(bhp + c01);
  f32x4 o0[4], o1[4];
#pragma unroll
  for (int m = 0; m < 4; ++m){
#pragma unroll
    for (int reg = 0; reg < 4; ++reg){
      float htld0 = tanh_f(ah0[m][reg] + bhv0[reg]);
      float htld1 = tanh_f(ah1[m][reg] + bhv1[reg]);
      float ht0 = bf2f((unsigned short)(htp0[m][reg >> 1] >> ((reg & 1) * 16)));
      float ht1 = bf2f((unsigned short)(htp1[m][reg >> 1] >> ((reg & 1) * 16)));
      float z0 = zk0[m][reg], z1 = zk1[m][reg];
      o0[m][reg] = (1.f - z0) * ht0 + z0 * htld0;
      o1[m][reg] = (1.f - z1) * ht1 + z1 * htld1;
    }
  }
  __syncthreads();   // (4) all stage-2 LDS reads done before P overlay

  // ---------- row sumsq: lane has 8 cols of its row; reduce across lq lanes ----------
#pragma unroll
  for (int m = 0; m < 4; ++m){
    const int row = m * 16 + l15;
    float s = 0.f;
#pragma unroll
    for (int reg = 0; reg < 4; ++reg)
      s += o0[m][reg]*o0[m][reg] + o1[m][reg]*o1[m][reg];
    s += __shfl_xor(s, 16, 64);
    s += __shfl_xor(s, 32, 64);
    if (lq == 0) P[row * 4 + w] = s;
  }
  __syncthreads();   // (5) partials visible

  // ---------- final: expmap0 + proj, f32x4 stores (wave fills full 128B line/row) ----------
#pragma unroll
  for (int m = 0; m < 4; ++m){
    const int row = m * 16 + l15;
    const f32x4 p4 = *(const f32x4*)(P + row * 4);   // broadcast within row group
    float ss = p4[0] + p4[1] + p4[2] + p4[3];
    float n = __builtin_amdgcn_sqrtf(ss);
    float sc = 1.f;
    if (n > 1e-20f){
      float th = tanh_f(n);
      th = fminf(th, 0.99999f);          // proj: maxnorm = 1 - 1e-5
      sc = th * rcp_f(n);
    }
    float* orow = out + (row0 + row) * D;
    f32x4 st0 = o0[m] * sc;
    f32x4 st1 = o1[m] * sc;
    *(f32x4*)(orow + c00) = st0;
    *(f32x4*)(orow + c01) = st1;
  }
}

extern "C" void kernel_launch(void* const* d_in, const int* in_sizes, int n_in,
                              void* d_out, int out_size, void* d_ws, size_t ws_size,
                              hipStream_t stream)
{
  const float* x   = (const float*)d_in[0];
  const float* h   = (const float*)d_in[1];
  const float* Wr  = (const float*)d_in[2];
  const float* brp = (const float*)d_in[3];
  const float* Wz  = (const float*)d_in[4];
  const float* bzp = (const float*)d_in[5];
  const float* Wh  = (const float*)d_in[6];
  const float* bhp = (const float*)d_in[7];
  unsigned short* wsp = (unsigned short*)d_ws;   // 3 * 32768 bf16 = 192KB packed weights

  prep_weights<<<192, 64, 0, stream>>>(Wr, Wz, Wh, wsp);
  gru_fused<<<262144 / BM, 256, 0, stream>>>(x, h, brp, bzp, bhp, wsp, (float*)d_out);
}

// Round 8
// 134.265 us; speedup vs baseline: 1.6346x; 1.6346x over previous
//
#include <hip/hip_runtime.h>
#include <hip/hip_bf16.h>

typedef __attribute__((ext_vector_type(4))) float f32x4;
typedef __attribute__((ext_vector_type(8))) short bf16x8;
typedef __attribute__((ext_vector_type(4))) short bf16x4;
typedef __attribute__((ext_vector_type(2))) unsigned int u32x2;

#define D 128
#define BM 32

__device__ __forceinline__ unsigned short f2bf(float f){
  union { float f; unsigned int i; } c; c.f = f;
  unsigned int i = c.i;
  i += 0x7fffu + ((i >> 16) & 1u);   // round-to-nearest-even
  return (unsigned short)(i >> 16);
}
__device__ __forceinline__ float bf2f(unsigned short u){
  union { float f; unsigned int i; } c; c.i = ((unsigned int)u) << 16; return c.f;
}
// pack two floats -> 2x bf16 in one u32 (v_cvt_pk_bf16_f32)
__device__ __forceinline__ unsigned int pk2(float a, float b){
  __hip_bfloat162 t = __float22bfloat162_rn(make_float2(a, b));
  return *reinterpret_cast<unsigned int*>(&t);
}
__device__ __forceinline__ float rcp_f(float x){ return __builtin_amdgcn_rcpf(x); }
__device__ __forceinline__ float exp2_f(float x){ return __builtin_amdgcn_exp2f(x); }
// sigmoid via v_exp+v_rcp: inf-safe
__device__ __forceinline__ float sigmoid_f(float t){
  return rcp_f(1.0f + exp2_f(-1.442695041f * t));
}
// tanh = 2*sigmoid(2t)-1: inf-safe
__device__ __forceinline__ float tanh_f(float t){
  return __builtin_fmaf(2.0f, rcp_f(1.0f + exp2_f(-2.885390082f * t)), -1.0f);
}

// Pack W[k=256][n=128] fp32 -> bf16 MFMA fragments:
// frag f = nf*8+kk ; lane l holds col = nf*16+(l&15), k = kk*32+(l>>4)*8+j (j=0..7)
// Used as the A-operand (A = W^T slice): lane l = outcol l&15, 8 consecutive k.
__global__ void prep_weights(const float* __restrict__ Wr, const float* __restrict__ Wz,
                             const float* __restrict__ Wh, unsigned short* __restrict__ wp)
{
  int w = blockIdx.x >> 6;          // 0:Wr 1:Wz 2:Wh
  int f = blockIdx.x & 63;          // nf*8 + kk
  int l = threadIdx.x;              // 0..63
  const float* src = (w == 0) ? Wr : ((w == 1) ? Wz : Wh);
  int nf = f >> 3, kk = f & 7;
  int col = nf * 16 + (l & 15);
  int k0  = kk * 32 + (l >> 4) * 8;
  unsigned short* dst = wp + w * 32768 + (f * 64 + l) * 8;
#pragma unroll
  for (int j = 0; j < 8; ++j)
    dst[j] = f2bf(src[(k0 + j) * D + col]);
}

// BM=32: 16KB LDS/block, 32 acc/wave -> (256,5): 20 waves/CU, 5 independent blocks/CU.
// R5/R7 lesson: the BM=64 variant is register-saturated at 64 AGPR + 64 arch; any
// added live state spills to scratch (FETCH/WRITE balloon). Halving the tile halves state.
__global__ __launch_bounds__(256, 5) void gru_fused(
    const float* __restrict__ x, const float* __restrict__ h,
    const float* __restrict__ brp, const float* __restrict__ bzp, const float* __restrict__ bhp,
    const unsigned short* __restrict__ wp, float* __restrict__ out)
{
  // A1: xh bf16 [32 rows][256 k] XOR-swizzled (16KB). r*h_tan overwrites the h-half in place.
  // P: f32 row-sumsq partials [32][4] (512B), overlays A1 after all stage-2 reads.
  __shared__ __align__(16) unsigned char A1[BM * 512];
  float* P = (float*)A1;

  const int tid = threadIdx.x;
  const int w   = tid >> 6;
  const int l   = tid & 63;
  const int l15 = l & 15;
  const int lq  = l >> 4;
  const size_t row0 = (size_t)blockIdx.x * BM;

  // ---------- phase 1: logmap0(x), logmap0(h) -> A1 bf16 (swizzled) ----------
  // 8 threads per row; interleaved x then h to keep live VGPRs low (R4 lesson).
  {
    const int row = tid >> 3;          // 0..31
    const int q   = tid & 7;           // 8 lanes per row
    const f32x4* xr = (const f32x4*)(x + (row0 + row) * D);
    const f32x4* hr = (const f32x4*)(h + (row0 + row) * D);
    f32x4 v[4];
    float ss = 0.f;
#pragma unroll
    for (int j = 0; j < 4; ++j){
      v[j] = xr[j * 8 + q];
      ss += v[j][0]*v[j][0] + v[j][1]*v[j][1] + v[j][2]*v[j][2] + v[j][3]*v[j][3];
    }
    ss += __shfl_xor(ss, 1, 64);
    ss += __shfl_xor(ss, 2, 64);
    ss += __shfl_xor(ss, 4, 64);
    // atanh(n)/n = 0.5*ln2*log2((1+n)*rcp(1-n)) * rcp(n)
    float n = __builtin_amdgcn_sqrtf(ss);
    float s = 1.f;
    if (n > 1e-20f)
      s = 0.34657359f * __builtin_amdgcn_logf((1.f + n) * rcp_f(1.f - n)) * rcp_f(n);
#pragma unroll
    for (int j = 0; j < 4; ++j){
      unsigned int byte = (unsigned)(row * 512 + (8 * j + q) * 8) ^ (unsigned)((row & 7) << 4);
      u32x2 pk; pk[0] = pk2(v[j][0] * s, v[j][1] * s); pk[1] = pk2(v[j][2] * s, v[j][3] * s);
      *(u32x2*)(A1 + byte) = pk;
    }
    ss = 0.f;
#pragma unroll
    for (int j = 0; j < 4; ++j){
      v[j] = hr[j * 8 + q];
      ss += v[j][0]*v[j][0] + v[j][1]*v[j][1] + v[j][2]*v[j][2] + v[j][3]*v[j][3];
    }
    ss += __shfl_xor(ss, 1, 64);
    ss += __shfl_xor(ss, 2, 64);
    ss += __shfl_xor(ss, 4, 64);
    n = __builtin_amdgcn_sqrtf(ss);
    s = 1.f;
    if (n > 1e-20f)
      s = 0.34657359f * __builtin_amdgcn_logf((1.f + n) * rcp_f(1.f - n)) * rcp_f(n);
#pragma unroll
    for (int j = 0; j < 4; ++j){
      unsigned int byte = (unsigned)(row * 512 + 256 + (8 * j + q) * 8) ^ (unsigned)((row & 7) << 4);
      u32x2 pk; pk[0] = pk2(v[j][0] * s, v[j][1] * s); pk[1] = pk2(v[j][2] * s, v[j][3] * s);
      *(u32x2*)(A1 + byte) = pk;
    }
  }
  __syncthreads();   // (1) A1 populated

  // ---------- stage 1: D = mfma(W^T frag, xh^T frag) ----------
  // wave w -> outcols [w*32, w*32+32), lane: row=m*16+l15 (m=0,1), cols c0+{0..3}.
  const unsigned short* pwr = wp + w * 8192;
  const unsigned short* pwz = wp + 32768 + w * 8192;

  f32x4 ar0[2], ar1[2], az0[2], az1[2];
#pragma unroll
  for (int m = 0; m < 2; ++m){ ar0[m] = 0; ar1[m] = 0; az0[m] = 0; az1[m] = 0; }

#pragma unroll 2
  for (int kk = 0; kk < 8; ++kk){
    const bf16x8 wr0 = *(const bf16x8*)(pwr + kk * 512 + l * 8);
    const bf16x8 wr1 = *(const bf16x8*)(pwr + 4096 + kk * 512 + l * 8);
    const bf16x8 wz0 = *(const bf16x8*)(pwz + kk * 512 + l * 8);
    const bf16x8 wz1 = *(const bf16x8*)(pwz + 4096 + kk * 512 + l * 8);
#pragma unroll
    for (int m = 0; m < 2; ++m){
      const int row = m * 16 + l15;
      unsigned int byte = (unsigned)(row * 512 + (kk * 32 + lq * 8) * 2) ^ (unsigned)((row & 7) << 4);
      const bf16x8 b = *(const bf16x8*)(A1 + byte);
      ar0[m] = __builtin_amdgcn_mfma_f32_16x16x32_bf16(wr0, b, ar0[m], 0, 0, 0);
      ar1[m] = __builtin_amdgcn_mfma_f32_16x16x32_bf16(wr1, b, ar1[m], 0, 0, 0);
      az0[m] = __builtin_amdgcn_mfma_f32_16x16x32_bf16(wz0, b, az0[m], 0, 0, 0);
      az1[m] = __builtin_amdgcn_mfma_f32_16x16x32_bf16(wz1, b, az1[m], 0, 0, 0);
    }
  }

  // ---------- epilogue 1: r,z; rh packed; ht stashed ----------
  const int c00 = w * 32 + lq * 4;
  const int c01 = c00 + 16;
  const f32x4 brv0 = *(const f32x4*)(brp + c00);
  const f32x4 brv1 = *(const f32x4*)(brp + c01);
  const f32x4 bzv0 = *(const f32x4*)(bzp + c00);
  const f32x4 bzv1 = *(const f32x4*)(bzp + c01);

  f32x4 zk0[2], zk1[2];
  u32x2 htp0[2], htp1[2];   // packed bf16 h_tan, 4 consecutive cols
  u32x2 rhp0[2], rhp1[2];   // packed bf16 r*h_tan
#pragma unroll
  for (int m = 0; m < 2; ++m){
    const int row = m * 16 + l15;
    const unsigned int swz = (unsigned)((row & 7) << 4);
    const bf16x4 h40 = *(const bf16x4*)(A1 + ((unsigned)(row * 512 + (128 + c00) * 2) ^ swz));
    const bf16x4 h41 = *(const bf16x4*)(A1 + ((unsigned)(row * 512 + (128 + c01) * 2) ^ swz));
    htp0[m] = *(const u32x2*)&h40;
    htp1[m] = *(const u32x2*)&h41;
    float rh0[4], rh1[4];
#pragma unroll
    for (int reg = 0; reg < 4; ++reg){
      float r0 = sigmoid_f(ar0[m][reg] + brv0[reg]);
      float r1 = sigmoid_f(ar1[m][reg] + brv1[reg]);
      zk0[m][reg] = sigmoid_f(az0[m][reg] + bzv0[reg]);
      zk1[m][reg] = sigmoid_f(az1[m][reg] + bzv1[reg]);
      rh0[reg] = r0 * bf2f((unsigned short)h40[reg]);
      rh1[reg] = r1 * bf2f((unsigned short)h41[reg]);
    }
    rhp0[m][0] = pk2(rh0[0], rh0[1]); rhp0[m][1] = pk2(rh0[2], rh0[3]);
    rhp1[m][0] = pk2(rh1[0], rh1[1]); rhp1[m][1] = pk2(rh1[2], rh1[3]);
  }
  __syncthreads();   // (2) all stage-1 LDS reads complete before in-place overwrite

#pragma unroll
  for (int m = 0; m < 2; ++m){
    const int row = m * 16 + l15;
    const unsigned int swz = (unsigned)((row & 7) << 4);
    *(u32x2*)(A1 + ((unsigned)(row * 512 + (128 + c00) * 2) ^ swz)) = rhp0[m];
    *(u32x2*)(A1 + ((unsigned)(row * 512 + (128 + c01) * 2) ^ swz)) = rhp1[m];
  }
  __syncthreads();   // (3) A1 now holds [x_tan | r*h_tan]

  // ---------- stage 2: [x_tan | r*h_tan] @ Wh ----------
  const unsigned short* pwh = wp + 65536 + w * 8192;
  f32x4 ah0[2], ah1[2];
#pragma unroll
  for (int m = 0; m < 2; ++m){ ah0[m] = 0; ah1[m] = 0; }

#pragma unroll 2
  for (int kk = 0; kk < 8; ++kk){
    const bf16x8 wh0 = *(const bf16x8*)(pwh + kk * 512 + l * 8);
    const bf16x8 wh1 = *(const bf16x8*)(pwh + 4096 + kk * 512 + l * 8);
#pragma unroll
    for (int m = 0; m < 2; ++m){
      const int row = m * 16 + l15;
      unsigned int byte = (unsigned)(row * 512 + (kk * 32 + lq * 8) * 2) ^ (unsigned)((row & 7) << 4);
      const bf16x8 b = *(const bf16x8*)(A1 + byte);
      ah0[m] = __builtin_amdgcn_mfma_f32_16x16x32_bf16(wh0, b, ah0[m], 0, 0, 0);
      ah1[m] = __builtin_amdgcn_mfma_f32_16x16x32_bf16(wh1, b, ah1[m], 0, 0, 0);
    }
  }

  // ---------- epilogue 2: h_new_tan in regs ----------
  const f32x4 bhv0 = *(const f32x4*)(bhp + c00);
  const f32x4 bhv1 = *(const f32x4*)(bhp + c01);
  f32x4 o0[2], o1[2];
#pragma unroll
  for (int m = 0; m < 2; ++m){
#pragma unroll
    for (int reg = 0; reg < 4; ++reg){
      float htld0 = tanh_f(ah0[m][reg] + bhv0[reg]);
      float htld1 = tanh_f(ah1[m][reg] + bhv1[reg]);
      float ht0 = bf2f((unsigned short)(htp0[m][reg >> 1] >> ((reg & 1) * 16)));
      float ht1 = bf2f((unsigned short)(htp1[m][reg >> 1] >> ((reg & 1) * 16)));
      float z0 = zk0[m][reg], z1 = zk1[m][reg];
      o0[m][reg] = (1.f - z0) * ht0 + z0 * htld0;
      o1[m][reg] = (1.f - z1) * ht1 + z1 * htld1;
    }
  }
  __syncthreads();   // (4) all stage-2 LDS reads done before P overlay

  // ---------- row sumsq: lane has 8 cols of its row; reduce across lq lanes ----------
#pragma unroll
  for (int m = 0; m < 2; ++m){
    const int row = m * 16 + l15;
    float s = 0.f;
#pragma unroll
    for (int reg = 0; reg < 4; ++reg)
      s += o0[m][reg]*o0[m][reg] + o1[m][reg]*o1[m][reg];
    s += __shfl_xor(s, 16, 64);
    s += __shfl_xor(s, 32, 64);
    if (lq == 0) P[row * 4 + w] = s;
  }
  __syncthreads();   // (5) partials visible

  // ---------- final: expmap0 + proj, f32x4 stores ----------
#pragma unroll
  for (int m = 0; m < 2; ++m){
    const int row = m * 16 + l15;
    const f32x4 p4 = *(const f32x4*)(P + row * 4);   // broadcast within row group
    float ss = p4[0] + p4[1] + p4[2] + p4[3];
    float n = __builtin_amdgcn_sqrtf(ss);
    float sc = 1.f;
    if (n > 1e-20f){
      float th = tanh_f(n);
      th = fminf(th, 0.99999f);          // proj: maxnorm = 1 - 1e-5
      sc = th * rcp_f(n);
    }
    float* orow = out + (row0 + row) * D;
    f32x4 st0 = o0[m] * sc;
    f32x4 st1 = o1[m] * sc;
    *(f32x4*)(orow + c00) = st0;
    *(f32x4*)(orow + c01) = st1;
  }
}

extern "C" void kernel_launch(void* const* d_in, const int* in_sizes, int n_in,
                              void* d_out, int out_size, void* d_ws, size_t ws_size,
                              hipStream_t stream)
{
  const float* x   = (const float*)d_in[0];
  const float* h   = (const float*)d_in[1];
  const float* Wr  = (const float*)d_in[2];
  const float* brp = (const float*)d_in[3];
  const float* Wz  = (const float*)d_in[4];
  const float* bzp = (const float*)d_in[5];
  const float* Wh  = (const float*)d_in[6];
  const float* bhp = (const float*)d_in[7];
  unsigned short* wsp = (unsigned short*)d_ws;   // 3 * 32768 bf16 = 192KB packed weights

  prep_weights<<<192, 64, 0, stream>>>(Wr, Wz, Wh, wsp);
  gru_fused<<<262144 / BM, 256, 0, stream>>>(x, h, brp, bzp, bhp, wsp, (float*)d_out);
}

// Round 9
// 124.782 us; speedup vs baseline: 1.7588x; 1.0760x over previous
//
#include <hip/hip_runtime.h>
#include <hip/hip_bf16.h>

typedef __attribute__((ext_vector_type(4))) float f32x4;
typedef __attribute__((ext_vector_type(8))) short bf16x8;
typedef __attribute__((ext_vector_type(4))) short bf16x4;
typedef __attribute__((ext_vector_type(2))) unsigned int u32x2;

#define D 128
#define BM 64

__device__ __forceinline__ unsigned short f2bf(float f){
  union { float f; unsigned int i; } c; c.f = f;
  unsigned int i = c.i;
  i += 0x7fffu + ((i >> 16) & 1u);   // round-to-nearest-even
  return (unsigned short)(i >> 16);
}
__device__ __forceinline__ float bf2f(unsigned short u){
  union { float f; unsigned int i; } c; c.i = ((unsigned int)u) << 16; return c.f;
}
// pack two floats -> 2x bf16 in one u32 (v_cvt_pk_bf16_f32)
__device__ __forceinline__ unsigned int pk2(float a, float b){
  __hip_bfloat162 t = __float22bfloat162_rn(make_float2(a, b));
  return *reinterpret_cast<unsigned int*>(&t);
}
__device__ __forceinline__ float rcp_f(float x){ return __builtin_amdgcn_rcpf(x); }
__device__ __forceinline__ float exp2_f(float x){ return __builtin_amdgcn_exp2f(x); }
// sigmoid via v_exp+v_rcp: inf-safe
__device__ __forceinline__ float sigmoid_f(float t){
  return rcp_f(1.0f + exp2_f(-1.442695041f * t));
}
// tanh = 2*sigmoid(2t)-1: inf-safe
__device__ __forceinline__ float tanh_f(float t){
  return __builtin_fmaf(2.0f, rcp_f(1.0f + exp2_f(-2.885390082f * t)), -1.0f);
}

// Pack W[k=256][n=128] fp32 -> bf16 MFMA fragments:
// frag f = nf*8+kk ; lane l holds col = nf*16+(l&15), k = kk*32+(l>>4)*8+j (j=0..7)
// Used as the A-operand (A = W^T slice): lane l = outcol l&15, 8 consecutive k.
__global__ void prep_weights(const float* __restrict__ Wr, const float* __restrict__ Wz,
                             const float* __restrict__ Wh, unsigned short* __restrict__ wp)
{
  int w = blockIdx.x >> 6;          // 0:Wr 1:Wz 2:Wh
  int f = blockIdx.x & 63;          // nf*8 + kk
  int l = threadIdx.x;              // 0..63
  const float* src = (w == 0) ? Wr : ((w == 1) ? Wz : Wh);
  int nf = f >> 3, kk = f & 7;
  int col = nf * 16 + (l & 15);
  int k0  = kk * 32 + (l >> 4) * 8;
  unsigned short* dst = wp + w * 32768 + (f * 64 + l) * 8;
#pragma unroll
  for (int j = 0; j < 8; ++j)
    dst[j] = f2bf(src[(k0 + j) * D + col]);
}

// (256,3): ~168-reg budget/wave. R4/R6/R7 all spilled at the (256,4)=128 budget
// (R5 sits exactly at 64 arch + 64 acc). 49KB LDS -> 3 blocks/CU = 12 waves/CU,
// equal to R5's *measured* occupancy, so the headroom is nearly free.
__global__ __launch_bounds__(256, 3) void gru_fused(
    const float* __restrict__ x, const float* __restrict__ h,
    const float* __restrict__ brp, const float* __restrict__ bzp, const float* __restrict__ bhp,
    const unsigned short* __restrict__ wp, float* __restrict__ out)
{
  // A1: xh bf16 [64 rows][256 k] XOR-swizzled (32KB) — never overwritten.
  // A2: r*h_tan bf16 [64 rows][128] XOR-swizzled (16KB) — written in ep1, read in stage2.
  // P : f32 row-sumsq partials [64][4] (1KB) — separate array, no overlay hazard.
  __shared__ __align__(16) unsigned char A1[BM * 512];
  __shared__ __align__(16) unsigned char A2[BM * 256];
  __shared__ float P[BM * 4];

  const int tid = threadIdx.x;
  const int w   = tid >> 6;
  const int l   = tid & 63;
  const int l15 = l & 15;
  const int lq  = l >> 4;
  const size_t row0 = (size_t)blockIdx.x * BM;

  const unsigned short* pwr = wp + w * 8192;
  const unsigned short* pwz = wp + 32768 + w * 8192;
  const unsigned short* pwh = wp + 65536 + w * 8192;

  // ---------- phase 1: logmap0(x), logmap0(h) -> A1 bf16 (swizzled) ----------
  // Interleaved (x then h) to keep live VGPRs low (R4 lesson).
  {
    const int row = tid >> 2;
    const int q   = tid & 3;
    const f32x4* xr = (const f32x4*)(x + (row0 + row) * D);
    const f32x4* hr = (const f32x4*)(h + (row0 + row) * D);
    f32x4 v[8];
    float ss = 0.f;
#pragma unroll
    for (int j = 0; j < 8; ++j){
      v[j] = xr[j * 4 + q];
      ss += v[j][0]*v[j][0] + v[j][1]*v[j][1] + v[j][2]*v[j][2] + v[j][3]*v[j][3];
    }
    ss += __shfl_xor(ss, 1, 64);
    ss += __shfl_xor(ss, 2, 64);
    // atanh(n)/n = 0.5*ln2*log2((1+n)*rcp(1-n)) * rcp(n)
    float n = __builtin_amdgcn_sqrtf(ss);
    float s = 1.f;
    if (n > 1e-20f)
      s = 0.34657359f * __builtin_amdgcn_logf((1.f + n) * rcp_f(1.f - n)) * rcp_f(n);
#pragma unroll
    for (int j = 0; j < 8; ++j){
      unsigned int byte = (unsigned)(row * 512 + (4 * j + q) * 8) ^ (unsigned)((row & 7) << 4);
      u32x2 pk; pk[0] = pk2(v[j][0] * s, v[j][1] * s); pk[1] = pk2(v[j][2] * s, v[j][3] * s);
      *(u32x2*)(A1 + byte) = pk;
    }
    ss = 0.f;
#pragma unroll
    for (int j = 0; j < 8; ++j){
      v[j] = hr[j * 4 + q];
      ss += v[j][0]*v[j][0] + v[j][1]*v[j][1] + v[j][2]*v[j][2] + v[j][3]*v[j][3];
    }
    ss += __shfl_xor(ss, 1, 64);
    ss += __shfl_xor(ss, 2, 64);
    n = __builtin_amdgcn_sqrtf(ss);
    s = 1.f;
    if (n > 1e-20f)
      s = 0.34657359f * __builtin_amdgcn_logf((1.f + n) * rcp_f(1.f - n)) * rcp_f(n);
#pragma unroll
    for (int j = 0; j < 8; ++j){
      unsigned int byte = (unsigned)(row * 512 + 256 + (4 * j + q) * 8) ^ (unsigned)((row & 7) << 4);
      u32x2 pk; pk[0] = pk2(v[j][0] * s, v[j][1] * s); pk[1] = pk2(v[j][2] * s, v[j][3] * s);
      *(u32x2*)(A1 + byte) = pk;
    }
  }

  // prefetch kk=0 stage-1 weight frags: VMEM latency overlaps barrier drain
  bf16x8 nwr0 = *(const bf16x8*)(pwr + 0 * 512 + l * 8);
  bf16x8 nwr1 = *(const bf16x8*)(pwr + 4096 + 0 * 512 + l * 8);
  bf16x8 nwz0 = *(const bf16x8*)(pwz + 0 * 512 + l * 8);
  bf16x8 nwz1 = *(const bf16x8*)(pwz + 4096 + 0 * 512 + l * 8);

  __syncthreads();   // (1) A1 ready

  // ---------- stage 1a: r,z = xh @ {Wr,Wz}, full K, software-pipelined weights ----------
  // wave w -> outcols [w*32, w*32+32), lane: row=m*16+l15, cols c0+{0..3}.
  f32x4 ar0[4], ar1[4], az0[4], az1[4];
#pragma unroll
  for (int m = 0; m < 4; ++m){ ar0[m] = 0; ar1[m] = 0; az0[m] = 0; az1[m] = 0; }

#pragma unroll
  for (int kk = 0; kk < 8; ++kk){
    const bf16x8 wr0 = nwr0, wr1 = nwr1, wz0 = nwz0, wz1 = nwz1;
    if (kk < 7){
      nwr0 = *(const bf16x8*)(pwr + (kk + 1) * 512 + l * 8);
      nwr1 = *(const bf16x8*)(pwr + 4096 + (kk + 1) * 512 + l * 8);
      nwz0 = *(const bf16x8*)(pwz + (kk + 1) * 512 + l * 8);
      nwz1 = *(const bf16x8*)(pwz + 4096 + (kk + 1) * 512 + l * 8);
    }
#pragma unroll
    for (int m = 0; m < 4; ++m){
      const int row = m * 16 + l15;
      unsigned int byte = (unsigned)(row * 512 + (kk * 32 + lq * 8) * 2) ^ (unsigned)((row & 7) << 4);
      const bf16x8 b = *(const bf16x8*)(A1 + byte);
      ar0[m] = __builtin_amdgcn_mfma_f32_16x16x32_bf16(wr0, b, ar0[m], 0, 0, 0);
      ar1[m] = __builtin_amdgcn_mfma_f32_16x16x32_bf16(wr1, b, ar1[m], 0, 0, 0);
      az0[m] = __builtin_amdgcn_mfma_f32_16x16x32_bf16(wz0, b, az0[m], 0, 0, 0);
      az1[m] = __builtin_amdgcn_mfma_f32_16x16x32_bf16(wz1, b, az1[m], 0, 0, 0);
    }
  }

  // ---------- epilogue 1: r,z; r*h_tan straight to A2 (no read-hazard -> no barrier) ----------
  const int c00 = w * 32 + lq * 4;
  const int c01 = c00 + 16;
  const f32x4 brv0 = *(const f32x4*)(brp + c00);
  const f32x4 brv1 = *(const f32x4*)(brp + c01);
  const f32x4 bzv0 = *(const f32x4*)(bzp + c00);
  const f32x4 bzv1 = *(const f32x4*)(bzp + c01);

  f32x4 zk0[4], zk1[4];
  u32x2 htp0[4], htp1[4];   // packed bf16 h_tan, 4 consecutive cols
#pragma unroll
  for (int m = 0; m < 4; ++m){
    const int row = m * 16 + l15;
    const unsigned int swz = (unsigned)((row & 7) << 4);
    const bf16x4 h40 = *(const bf16x4*)(A1 + ((unsigned)(row * 512 + (128 + c00) * 2) ^ swz));
    const bf16x4 h41 = *(const bf16x4*)(A1 + ((unsigned)(row * 512 + (128 + c01) * 2) ^ swz));
    htp0[m] = *(const u32x2*)&h40;
    htp1[m] = *(const u32x2*)&h41;
    float rh0[4], rh1[4];
#pragma unroll
    for (int reg = 0; reg < 4; ++reg){
      float r0 = sigmoid_f(ar0[m][reg] + brv0[reg]);
      float r1 = sigmoid_f(ar1[m][reg] + brv1[reg]);
      zk0[m][reg] = sigmoid_f(az0[m][reg] + bzv0[reg]);
      zk1[m][reg] = sigmoid_f(az1[m][reg] + bzv1[reg]);
      rh0[reg] = r0 * bf2f((unsigned short)h40[reg]);
      rh1[reg] = r1 * bf2f((unsigned short)h41[reg]);
    }
    u32x2 p0; p0[0] = pk2(rh0[0], rh0[1]); p0[1] = pk2(rh0[2], rh0[3]);
    u32x2 p1; p1[0] = pk2(rh1[0], rh1[1]); p1[1] = pk2(rh1[2], rh1[3]);
    *(u32x2*)(A2 + ((unsigned)(row * 256 + c00 * 2) ^ swz)) = p0;
    *(u32x2*)(A2 + ((unsigned)(row * 256 + c01 * 2) ^ swz)) = p1;
  }

  // ---------- stage 1b: x_tan @ Wh[0:128] (independent of r) — pre-barrier overlap ----------
  f32x4 ah0[4], ah1[4];
#pragma unroll
  for (int m = 0; m < 4; ++m){ ah0[m] = 0; ah1[m] = 0; }
  bf16x8 nwh0 = *(const bf16x8*)(pwh + 0 * 512 + l * 8);
  bf16x8 nwh1 = *(const bf16x8*)(pwh + 4096 + 0 * 512 + l * 8);
#pragma unroll
  for (int kk = 0; kk < 4; ++kk){
    const bf16x8 wh0 = nwh0, wh1 = nwh1;
    {
      const int kn = (kk < 3) ? (kk + 1) : 4;   // last prefetch targets stage-2's kk=4
      nwh0 = *(const bf16x8*)(pwh + kn * 512 + l * 8);
      nwh1 = *(const bf16x8*)(pwh + 4096 + kn * 512 + l * 8);
    }
#pragma unroll
    for (int m = 0; m < 4; ++m){
      const int row = m * 16 + l15;
      unsigned int byte = (unsigned)(row * 512 + (kk * 32 + lq * 8) * 2) ^ (unsigned)((row & 7) << 4);
      const bf16x8 b = *(const bf16x8*)(A1 + byte);
      ah0[m] = __builtin_amdgcn_mfma_f32_16x16x32_bf16(wh0, b, ah0[m], 0, 0, 0);
      ah1[m] = __builtin_amdgcn_mfma_f32_16x16x32_bf16(wh1, b, ah1[m], 0, 0, 0);
    }
  }

  __syncthreads();   // (2) A2 ready

  // ---------- stage 2: += (r*h_tan) @ Wh[128:256] — halved post-barrier tail ----------
#pragma unroll
  for (int kk = 4; kk < 8; ++kk){
    const bf16x8 wh0 = nwh0, wh1 = nwh1;
    if (kk < 7){
      nwh0 = *(const bf16x8*)(pwh + (kk + 1) * 512 + l * 8);
      nwh1 = *(const bf16x8*)(pwh + 4096 + (kk + 1) * 512 + l * 8);
    }
#pragma unroll
    for (int m = 0; m < 4; ++m){
      const int row = m * 16 + l15;
      unsigned int byte = (unsigned)(row * 256 + ((kk - 4) * 32 + lq * 8) * 2) ^ (unsigned)((row & 7) << 4);
      const bf16x8 b = *(const bf16x8*)(A2 + byte);
      ah0[m] = __builtin_amdgcn_mfma_f32_16x16x32_bf16(wh0, b, ah0[m], 0, 0, 0);
      ah1[m] = __builtin_amdgcn_mfma_f32_16x16x32_bf16(wh1, b, ah1[m], 0, 0, 0);
    }
  }

  // ---------- epilogue 2: h_new_tan in regs; partial norms to P ----------
  const f32x4 bhv0 = *(const f32x4*)(bhp + c00);
  const f32x4 bhv1 = *(const f32x4*)(bhp + c01);
  f32x4 o0[4], o1[4];
#pragma unroll
  for (int m = 0; m < 4; ++m){
#pragma unroll
    for (int reg = 0; reg < 4; ++reg){
      float htld0 = tanh_f(ah0[m][reg] + bhv0[reg]);
      float htld1 = tanh_f(ah1[m][reg] + bhv1[reg]);
      float ht0 = bf2f((unsigned short)(htp0[m][reg >> 1] >> ((reg & 1) * 16)));
      float ht1 = bf2f((unsigned short)(htp1[m][reg >> 1] >> ((reg & 1) * 16)));
      float z0 = zk0[m][reg], z1 = zk1[m][reg];
      o0[m][reg] = (1.f - z0) * ht0 + z0 * htld0;
      o1[m][reg] = (1.f - z1) * ht1 + z1 * htld1;
    }
    const int row = m * 16 + l15;
    float s = 0.f;
#pragma unroll
    for (int reg = 0; reg < 4; ++reg)
      s += o0[m][reg]*o0[m][reg] + o1[m][reg]*o1[m][reg];
    s += __shfl_xor(s, 16, 64);
    s += __shfl_xor(s, 32, 64);
    if (lq == 0) P[row * 4 + w] = s;
  }
  __syncthreads();   // (3) P ready

  // ---------- final: expmap0 + proj, f32x4 stores (wave fills full 128B line/row) ----------
#pragma unroll
  for (int m = 0; m < 4; ++m){
    const int row = m * 16 + l15;
    const f32x4 p4 = *(const f32x4*)(P + row * 4);   // broadcast within row group
    float ss = p4[0] + p4[1] + p4[2] + p4[3];
    float n = __builtin_amdgcn_sqrtf(ss);
    float sc = 1.f;
    if (n > 1e-20f){
      float th = tanh_f(n);
      th = fminf(th, 0.99999f);          // proj: maxnorm = 1 - 1e-5
      sc = th * rcp_f(n);
    }
    float* orow = out + (row0 + row) * D;
    f32x4 st0 = o0[m] * sc;
    f32x4 st1 = o1[m] * sc;
    *(f32x4*)(orow + c00) = st0;
    *(f32x4*)(orow + c01) = st1;
  }
}

extern "C" void kernel_launch(void* const* d_in, const int* in_sizes, int n_in,
                              void* d_out, int out_size, void* d_ws, size_t ws_size,
                              hipStream_t stream)
{
  const float* x   = (const float*)d_in[0];
  const float* h   = (const float*)d_in[1];
  const float* Wr  = (const float*)d_in[2];
  const float* brp = (const float*)d_in[3];
  const float* Wz  = (const float*)d_in[4];
  const float* bzp = (const float*)d_in[5];
  const float* Wh  = (const float*)d_in[6];
  const float* bhp = (const float*)d_in[7];
  unsigned short* wsp = (unsigned short*)d_ws;   // 3 * 32768 bf16 = 192KB packed weights

  prep_weights<<<192, 64, 0, stream>>>(Wr, Wz, Wh, wsp);
  gru_fused<<<262144 / BM, 256, 0, stream>>>(x, h, brp, bzp, bhp, wsp, (float*)d_out);
}